// Round 3
// baseline (151.929 us; speedup 1.0000x reference)
//
#include <hip/hip_runtime.h>
#include <hip/hip_bf16.h>

// Dims (fixed): B=64, R=5, N=512, A=64, U=128
typedef __attribute__((ext_vector_type(4))) float f32x4;
typedef __attribute__((ext_vector_type(8))) short s16x8;
typedef __attribute__((ext_vector_type(4))) int i32x4;

__device__ __forceinline__ unsigned short f2bf(float f) {
  __hip_bfloat16 h = __float2bfloat16(f);
  return __builtin_bit_cast(unsigned short, h);
}

// ---- K0a: features [64][512][64] f32 -> FT [64][64][512] bf16 (transpose+cvt) ----
__global__ void k_ft(const float* __restrict__ F, unsigned short* __restrict__ FT) {
  __shared__ float t[64][65];
  const int b  = blockIdx.x >> 3;
  const int m0 = (blockIdx.x & 7) * 64;
  const int tid = threadIdx.x;  // 256
  {
    const int row = tid >> 2, ac = (tid & 3) * 16;
    const float* src = F + ((size_t)b * 512 + m0 + row) * 64 + ac;
    #pragma unroll
    for (int j = 0; j < 4; ++j) {
      f32x4 v = *(const f32x4*)(src + j * 4);
      t[row][ac + j * 4 + 0] = v[0]; t[row][ac + j * 4 + 1] = v[1];
      t[row][ac + j * 4 + 2] = v[2]; t[row][ac + j * 4 + 3] = v[3];
    }
  }
  __syncthreads();
  {
    const int a = tid >> 2, mc = (tid & 3) * 16;
    unsigned short* dst = FT + ((size_t)b * 64 + a) * 512 + m0 + mc;
    s16x8 p0, p1;
    #pragma unroll
    for (int j = 0; j < 8; ++j) {
      p0[j] = (short)f2bf(t[mc + j][a]);
      p1[j] = (short)f2bf(t[mc + 8 + j][a]);
    }
    *(s16x8*)(dst) = p0;
    *(s16x8*)(dst + 8) = p1;
  }
}

// ---- K0b: kernel [5][64][128] f32 -> KT [128][320] bf16 ; bsum[u] = sum_r bias ----
__global__ void k_kt(const float* __restrict__ K, const float* __restrict__ bias,
                     unsigned short* __restrict__ KT, float* __restrict__ bsum) {
  const int gtid = threadIdx.x + blockIdx.x * blockDim.x;
  for (int idx = gtid; idx < 128 * 320; idx += blockDim.x * gridDim.x) {
    const int u = idx / 320, ra = idx % 320;           // ra = r*64 + a
    KT[idx] = f2bf(K[(size_t)ra * 128 + u]);
  }
  if (gtid < 128) {
    float s = 0.f;
    #pragma unroll
    for (int r = 0; r < 5; ++r) s += bias[r * 128 + gtid];
    bsum[gtid] = s;
  }
}

// ---- Fused v3: r-outer, linear-stream adjacency via per-wave LDS queues, barrier-free.
// Per block: 64 n-rows. Per wave: 16 n-rows, full pipeline:
//   stage s=(r,mc): load Adj[b][r][rows][mc*128..+128] contiguous (1KB/instr) -> regs
//   -> ds_write own LDS queue -> ds_read B-frags -> MFMA acc[at] (agg_r^T)
//   at end of r: shfl-redistribute agg_r to A-frags -> MFMA out_acc += agg_r @ K_r
__global__ __launch_bounds__(256, 2) void k_fused(const float* __restrict__ Adj,
                                                  const unsigned short* __restrict__ FT,
                                                  const unsigned short* __restrict__ KT,
                                                  const float* __restrict__ bsum,
                                                  float* __restrict__ out) {
  __shared__ float lds[2][4][16][128];   // [buf][wave][row][m] = 64 KB
  const int b  = blockIdx.x >> 3;
  const int nt = blockIdx.x & 7;
  const int w  = threadIdx.x >> 6;
  const int l  = threadIdx.x & 63;
  const int l15 = l & 15, g = l >> 4;

  const float* adjW = Adj + (size_t)b * 5 * 262144 + (size_t)(nt * 64 + w * 16) * 512;
  const int srow = l >> 5;           // staging row within pair
  const int scol = (l & 31) * 4;     // staging float col within 128

  f32x4 G[8];
  // prologue: stage 0 (r=0, mc=0)
  #pragma unroll
  for (int i = 0; i < 8; ++i)
    G[i] = *(const f32x4*)(adjW + (size_t)(i * 2 + srow) * 512 + scol);
  #pragma unroll
  for (int i = 0; i < 8; ++i)
    *(f32x4*)&lds[0][w][i * 2 + srow][scol] = G[i];

  f32x4 out_acc[8];
  #pragma unroll
  for (int u = 0; u < 8; ++u) out_acc[u] = (f32x4)0.f;
  f32x4 acc[4];
  #pragma unroll
  for (int at = 0; at < 4; ++at) acc[at] = (f32x4)0.f;

  const unsigned short* ftW = FT + (size_t)b * 64 * 512;

  #pragma unroll
  for (int s = 0; s < 20; ++s) {
    const int r = s >> 2, mc = s & 3;
    const int buf = s & 1;

    // issue next stage's global loads (T14: latency hides under this stage's compute)
    if (s < 19) {
      const int r1 = (s + 1) >> 2, mc1 = (s + 1) & 3;
      const float* p = adjW + (size_t)r1 * 262144 + mc1 * 128;
      #pragma unroll
      for (int i = 0; i < 8; ++i)
        G[i] = *(const f32x4*)(p + (size_t)(i * 2 + srow) * 512 + scol);
    }

    // compute current stage: K-chunk m = mc*128 .. +128
    #pragma unroll
    for (int ksl = 0; ksl < 4; ++ksl) {
      const int m = mc * 128 + ksl * 32 + g * 8;
      f32x4 lo = *(const f32x4*)&lds[buf][w][l15][ksl * 32 + g * 8];
      f32x4 hi = *(const f32x4*)&lds[buf][w][l15][ksl * 32 + g * 8 + 4];
      s16x8 bfrag;
      #pragma unroll
      for (int j = 0; j < 4; ++j) {
        bfrag[j]     = (short)f2bf(lo[j]);
        bfrag[4 + j] = (short)f2bf(hi[j]);
      }
      #pragma unroll
      for (int at = 0; at < 4; ++at) {
        s16x8 ff = *(const s16x8*)(ftW + (size_t)(at * 16 + l15) * 512 + m);
        acc[at] = __builtin_amdgcn_mfma_f32_16x16x32_bf16(ff, bfrag, acc[at], 0, 0, 0);
      }
    }

    // end of relation r: fold agg_r into out_acc via in-register redistribution
    if (mc == 3) {
      // lane (l15,g) holds agg_r[a = at*16+g*4+t][n-col = l15] in acc[at][t]
      int pk0[4], pk1[4];
      #pragma unroll
      for (int at = 0; at < 4; ++at) {
        pk0[at] = (int)((unsigned)f2bf(acc[at][0]) | ((unsigned)f2bf(acc[at][1]) << 16));
        pk1[at] = (int)((unsigned)f2bf(acc[at][2]) | ((unsigned)f2bf(acc[at][3]) << 16));
      }
      const int sel = g >> 1;
      const int sl0 = ((g & 1) * 2) * 16 + l15;   // source lane for a-offset low half
      const int sl1 = sl0 + 16;
      #pragma unroll
      for (int ks2 = 0; ks2 < 2; ++ks2) {
        const int at0 = ks2 * 2, at1 = at0 + 1;
        int j0a = __shfl(pk0[at0], sl0), j0b = __shfl(pk0[at1], sl0);
        int j1a = __shfl(pk1[at0], sl0), j1b = __shfl(pk1[at1], sl0);
        int j2a = __shfl(pk0[at0], sl1), j2b = __shfl(pk0[at1], sl1);
        int j3a = __shfl(pk1[at0], sl1), j3b = __shfl(pk1[at1], sl1);
        i32x4 afi;
        afi[0] = sel ? j0b : j0a;
        afi[1] = sel ? j1b : j1a;
        afi[2] = sel ? j2b : j2a;
        afi[3] = sel ? j3b : j3a;
        s16x8 af = __builtin_bit_cast(s16x8, afi);
        #pragma unroll
        for (int ut = 0; ut < 8; ++ut) {
          s16x8 kf = *(const s16x8*)(KT + (size_t)(ut * 16 + l15) * 320 + r * 64 + ks2 * 32 + g * 8);
          out_acc[ut] = __builtin_amdgcn_mfma_f32_16x16x32_bf16(af, kf, out_acc[ut], 0, 0, 0);
        }
      }
      #pragma unroll
      for (int at = 0; at < 4; ++at) acc[at] = (f32x4)0.f;
    }

    // write next stage into the other buffer (compiler inserts the vmcnt waits)
    if (s < 19) {
      #pragma unroll
      for (int i = 0; i < 8; ++i)
        *(f32x4*)&lds[buf ^ 1][w][i * 2 + srow][scol] = G[i];
    }
  }

  // epilogue: D2 col=l15 -> u, row=g*4+t -> n
  #pragma unroll
  for (int ut = 0; ut < 8; ++ut) {
    const int u = ut * 16 + l15;
    const float bs = bsum[u];
    float* op = out + ((size_t)b * 512 + nt * 64 + w * 16 + g * 4) * 128 + u;
    #pragma unroll
    for (int t = 0; t < 4; ++t) {
      float vv = out_acc[ut][t] + bs;
      op[(size_t)t * 128] = vv > 0.f ? vv : 0.f;
    }
  }
}

extern "C" void kernel_launch(void* const* d_in, const int* in_sizes, int n_in,
                              void* d_out, int out_size, void* d_ws, size_t ws_size,
                              hipStream_t stream) {
  const float* adj  = (const float*)d_in[0];   // [64][5][512][512]
  const float* feat = (const float*)d_in[1];   // [64][512][64]
  const float* kern = (const float*)d_in[2];   // [5][64][128]
  const float* bias = (const float*)d_in[3];   // [5][1][128]
  float* out = (float*)d_out;                  // [64][512][128] f32

  char* ws = (char*)d_ws;
  unsigned short* FT   = (unsigned short*)ws;                  // 64*64*512*2 = 4,194,304 B
  unsigned short* KT   = (unsigned short*)(ws + 4194304);      // 128*320*2   =    81,920 B
  float*          bsum = (float*)(ws + 4194304 + 81920);       // 128*4       =       512 B

  hipLaunchKernelGGL(k_ft,    dim3(512), dim3(256), 0, stream, feat, FT);
  hipLaunchKernelGGL(k_kt,    dim3(160), dim3(256), 0, stream, kern, bias, KT, bsum);
  hipLaunchKernelGGL(k_fused, dim3(512), dim3(256), 0, stream, adj, FT, KT, bsum, out);
  (void)in_sizes; (void)n_in; (void)out_size; (void)ws_size;
}

// Round 4
// 97.416 us; speedup vs baseline: 1.5596x; 1.5596x over previous
//
#include <hip/hip_runtime.h>
#include <hip/hip_bf16.h>

// Dims (fixed): B=64, R=5, N=512, A=64, U=128
typedef __attribute__((ext_vector_type(4))) float f32x4;
typedef __attribute__((ext_vector_type(8))) short s16x8;
typedef __attribute__((ext_vector_type(4))) short s16x4;

__device__ __forceinline__ unsigned short f2bf(float f) {
  __hip_bfloat16 h = __float2bfloat16(f);
  return __builtin_bit_cast(unsigned short, h);
}

// ---- K0a: features [64][512][64] f32 -> FT [64][64][512] bf16 (transpose+cvt) ----
__global__ void k_ft(const float* __restrict__ F, unsigned short* __restrict__ FT) {
  __shared__ float t[64][65];
  const int b  = blockIdx.x >> 3;
  const int m0 = (blockIdx.x & 7) * 64;
  const int tid = threadIdx.x;  // 256
  {
    const int row = tid >> 2, ac = (tid & 3) * 16;
    const float* src = F + ((size_t)b * 512 + m0 + row) * 64 + ac;
    #pragma unroll
    for (int j = 0; j < 4; ++j) {
      f32x4 v = *(const f32x4*)(src + j * 4);
      t[row][ac + j * 4 + 0] = v[0]; t[row][ac + j * 4 + 1] = v[1];
      t[row][ac + j * 4 + 2] = v[2]; t[row][ac + j * 4 + 3] = v[3];
    }
  }
  __syncthreads();
  {
    const int a = tid >> 2, mc = (tid & 3) * 16;
    unsigned short* dst = FT + ((size_t)b * 64 + a) * 512 + m0 + mc;
    s16x8 p0, p1;
    #pragma unroll
    for (int j = 0; j < 8; ++j) {
      p0[j] = (short)f2bf(t[mc + j][a]);
      p1[j] = (short)f2bf(t[mc + 8 + j][a]);
    }
    *(s16x8*)(dst) = p0;
    *(s16x8*)(dst + 8) = p1;
  }
}

// ---- K0b: kernel [5][64][128] f32 -> KT [128][320] bf16 ; bsum[u] = sum_r bias ----
__global__ void k_kt(const float* __restrict__ K, const float* __restrict__ bias,
                     unsigned short* __restrict__ KT, float* __restrict__ bsum) {
  const int gtid = threadIdx.x + blockIdx.x * blockDim.x;
  for (int idx = gtid; idx < 128 * 320; idx += blockDim.x * gridDim.x) {
    const int u = idx / 320, ra = idx % 320;           // ra = r*64 + a
    KT[idx] = f2bf(K[(size_t)ra * 128 + u]);
  }
  if (gtid < 128) {
    float s = 0.f;
    #pragma unroll
    for (int r = 0; r < 5; ++r) s += bias[r * 128 + gtid];
    bsum[gtid] = s;
  }
}

// ---- Fused v4: round-2 skeleton + contiguous-512B adjacency ingress via
// per-wave double-buffered bf16 LDS reorder queue. Barrier-free (per-wave
// regions, lgkm ordering). Stages s = ks4*5 + r: ks4-outer (ffrag reuse
// across 5 relations), r-inner. acc[5][4] as in round 2.
__global__ __launch_bounds__(256, 2) void k_fused(const float* __restrict__ Adj,
                                                  const unsigned short* __restrict__ FT,
                                                  const unsigned short* __restrict__ KT,
                                                  const float* __restrict__ bsum,
                                                  float* __restrict__ out) {
  __shared__ unsigned short q[4][2][16][136];   // per-wave dbuf queue: 34,816 B
  __shared__ unsigned short ag[4][16][328];     // per-wave agg tile:   41,984 B  (total 76.8 KB)
  const int b  = blockIdx.x >> 3;
  const int nt = blockIdx.x & 7;
  const int w  = threadIdx.x >> 6;
  const int l  = threadIdx.x & 63;
  const int l15 = l & 15, g = l >> 4;

  const float* adjW = Adj + (size_t)b * 5 * 262144 + (size_t)(nt * 64 + w * 16) * 512;
  const unsigned short* ftW = FT + (size_t)b * 64 * 512;
  const int srow = l >> 5;          // row within pair
  const int scol = (l & 31) * 4;    // float col within 128-chunk

  unsigned short (*Q)[16][136] = q[w];
  unsigned short (*agw)[328] = ag[w];

  f32x4 G[8];
  // prologue: stage (ks4=0, r=0): 16 rows x 512B contiguous (1KB per instr)
  #pragma unroll
  for (int i = 0; i < 8; ++i)
    G[i] = *(const f32x4*)(adjW + (size_t)(i * 2 + srow) * 512 + scol);
  #pragma unroll
  for (int i = 0; i < 8; ++i) {
    s16x4 pk;
    pk[0] = (short)f2bf(G[i][0]); pk[1] = (short)f2bf(G[i][1]);
    pk[2] = (short)f2bf(G[i][2]); pk[3] = (short)f2bf(G[i][3]);
    *(s16x4*)&Q[0][i * 2 + srow][scol] = pk;
  }

  f32x4 acc[5][4];
  #pragma unroll
  for (int r = 0; r < 5; ++r)
    #pragma unroll
    for (int at = 0; at < 4; ++at) acc[r][at] = (f32x4)0.f;

  int cur = 0;
  for (int ks4 = 0; ks4 < 4; ++ks4) {
    // FT frags for this 128-col K-chunk, reused across all 5 relations (64 VGPR)
    s16x8 ffrag[4][4];
    #pragma unroll
    for (int ksl = 0; ksl < 4; ++ksl)
      #pragma unroll
      for (int at = 0; at < 4; ++at)
        ffrag[ksl][at] = *(const s16x8*)(ftW + (size_t)(at * 16 + l15) * 512 + ks4 * 128 + ksl * 32 + g * 8);

    #pragma unroll
    for (int r = 0; r < 5; ++r) {
      // issue next stage's global loads (hides under this stage's compute + other waves)
      const bool have_next = (r < 4) || (ks4 < 3);
      if (have_next) {
        const int rn = (r == 4) ? 0 : r + 1;
        const int kn = (r == 4) ? ks4 + 1 : ks4;
        const float* p = adjW + (size_t)rn * 262144 + (size_t)kn * 128;
        #pragma unroll
        for (int i = 0; i < 8; ++i)
          G[i] = *(const f32x4*)(p + (size_t)(i * 2 + srow) * 512 + scol);
      }

      // compute current stage from Q[cur]
      #pragma unroll
      for (int ksl = 0; ksl < 4; ++ksl) {
        s16x8 bfrag = *(const s16x8*)&Q[cur][l15][ksl * 32 + g * 8];
        acc[r][0] = __builtin_amdgcn_mfma_f32_16x16x32_bf16(ffrag[ksl][0], bfrag, acc[r][0], 0, 0, 0);
        acc[r][1] = __builtin_amdgcn_mfma_f32_16x16x32_bf16(ffrag[ksl][1], bfrag, acc[r][1], 0, 0, 0);
        acc[r][2] = __builtin_amdgcn_mfma_f32_16x16x32_bf16(ffrag[ksl][2], bfrag, acc[r][2], 0, 0, 0);
        acc[r][3] = __builtin_amdgcn_mfma_f32_16x16x32_bf16(ffrag[ksl][3], bfrag, acc[r][3], 0, 0, 0);
      }

      // cvt + write next stage into the other buffer
      if (have_next) {
        #pragma unroll
        for (int i = 0; i < 8; ++i) {
          s16x4 pk;
          pk[0] = (short)f2bf(G[i][0]); pk[1] = (short)f2bf(G[i][1]);
          pk[2] = (short)f2bf(G[i][2]); pk[3] = (short)f2bf(G[i][3]);
          *(s16x4*)&Q[cur ^ 1][i * 2 + srow][scol] = pk;
        }
        cur ^= 1;
      }
    }
  }

  // phase 2: lane (l15,g) holds agg[n-row = l15][a = at*16 + g*4 + t] in acc[r][at][t]
  #pragma unroll
  for (int r = 0; r < 5; ++r)
    #pragma unroll
    for (int at = 0; at < 4; ++at) {
      s16x4 pk;
      pk[0] = (short)f2bf(acc[r][at][0]); pk[1] = (short)f2bf(acc[r][at][1]);
      pk[2] = (short)f2bf(acc[r][at][2]); pk[3] = (short)f2bf(acc[r][at][3]);
      *(s16x4*)&agw[l15][r * 64 + at * 16 + g * 4] = pk;
    }
  // no barrier needed: per-wave region, in-wave lgkm ordering

  // phase 3: out-GEMM K=320, A from own ag tile, B = KT (L2-resident)
  f32x4 o[8];
  #pragma unroll
  for (int ut = 0; ut < 8; ++ut) o[ut] = (f32x4)0.f;

  #pragma unroll 2
  for (int ks = 0; ks < 10; ++ks) {
    s16x8 af = *(const s16x8*)&agw[l15][ks * 32 + g * 8];
    #pragma unroll
    for (int ut = 0; ut < 8; ++ut) {
      s16x8 kf = *(const s16x8*)(KT + (size_t)(ut * 16 + l15) * 320 + ks * 32 + g * 8);
      o[ut] = __builtin_amdgcn_mfma_f32_16x16x32_bf16(af, kf, o[ut], 0, 0, 0);
    }
  }

  // epilogue: D2 col=l15 -> u, row=g*4+t -> n
  #pragma unroll
  for (int ut = 0; ut < 8; ++ut) {
    const int u = ut * 16 + l15;
    const float bs = bsum[u];
    float* op = out + ((size_t)b * 512 + nt * 64 + w * 16 + g * 4) * 128 + u;
    #pragma unroll
    for (int t = 0; t < 4; ++t) {
      float vv = o[ut][t] + bs;
      op[(size_t)t * 128] = vv > 0.f ? vv : 0.f;
    }
  }
}

extern "C" void kernel_launch(void* const* d_in, const int* in_sizes, int n_in,
                              void* d_out, int out_size, void* d_ws, size_t ws_size,
                              hipStream_t stream) {
  const float* adj  = (const float*)d_in[0];   // [64][5][512][512]
  const float* feat = (const float*)d_in[1];   // [64][512][64]
  const float* kern = (const float*)d_in[2];   // [5][64][128]
  const float* bias = (const float*)d_in[3];   // [5][1][128]
  float* out = (float*)d_out;                  // [64][512][128] f32

  char* ws = (char*)d_ws;
  unsigned short* FT   = (unsigned short*)ws;                  // 64*64*512*2 = 4,194,304 B
  unsigned short* KT   = (unsigned short*)(ws + 4194304);      // 128*320*2   =    81,920 B
  float*          bsum = (float*)(ws + 4194304 + 81920);       // 128*4       =       512 B

  hipLaunchKernelGGL(k_ft,    dim3(512), dim3(256), 0, stream, feat, FT);
  hipLaunchKernelGGL(k_kt,    dim3(160), dim3(256), 0, stream, kern, bias, KT, bsum);
  hipLaunchKernelGGL(k_fused, dim3(512), dim3(256), 0, stream, adj, FT, KT, bsum, out);
  (void)in_sizes; (void)n_in; (void)out_size; (void)ws_size;
}